// Round 13
// baseline (212.735 us; speedup 1.0000x reference)
//
#include <hip/hip_runtime.h>

// GCN on MI355X — round 13: instruction-count cuts on the two biggest kernels.
//  1) k_agg inner loop on packed fp32 (v_pk_fma_f32/v_pk_max_f32 via
//     ext_vector(2) + __builtin_elementwise_*): 6 -> 3 VALU inst per edge.
//  2) k_mlp C->A staging: pack the lane's two h2 columns (l15, 16+l15) into
//     one uint -> 8 ds_write_b32 per chunk (was 16 ds_write_b16). The k-order
//     permutation this induces is folded into Bt2's layout in k_init (MFMA
//     contracts over slots; A/B just need to agree on the bijection).
//  Structure (bucket sort, rank-1 reconstruction, 6-dispatch chain) from r12.

#define HD 128
#define HD2 256
#define BSHIFT 8             // 256 nodes per bucket -> 391 buckets
#define BNODES 256
#define SRCBITS 17           // N=100000 < 2^17

typedef __attribute__((ext_vector_type(8))) short bf8_t;   // 8 x bf16 (4 VGPR)
typedef __attribute__((ext_vector_type(4))) float f32x4;
typedef __attribute__((ext_vector_type(2))) float f32x2;

static inline size_t align256(size_t x) { return (x + 255) & ~(size_t)255; }

__device__ inline ushort f2bf(float f) {            // RNE f32 -> bf16
    uint u = __float_as_uint(f);
    uint r = u + 0x7fffu + ((u >> 16) & 1u);
    return (ushort)(r >> 16);
}
__device__ inline uint packbf(float a, float b) {
    return (uint)f2bf(a) | ((uint)f2bf(b) << 16);
}
__device__ inline f32x2 pk_fma(f32x2 a, f32x2 b, f32x2 c) {
#if __has_builtin(__builtin_elementwise_fma)
    return __builtin_elementwise_fma(a, b, c);
#else
    return a * b + c;
#endif
}
__device__ inline f32x2 pk_relu(f32x2 a) {
#if __has_builtin(__builtin_elementwise_max)
    return __builtin_elementwise_max(a, (f32x2){0.f, 0.f});
#else
    f32x2 r; r.x = fmaxf(a.x, 0.f); r.y = fmaxf(a.y, 0.f); return r;
#endif
}

// prepB (weights -> bf16 chunk layout) + zero bfill. 128 blocks x 256.
// Bt2 gets the paired-column k-permutation: within each 32-k chunk, slot s
// holds k = (s>>1) + 16*(s&1)  (matches k_mlp's packed staging order).
__global__ void k_init(const float* __restrict__ W2, const float* __restrict__ Wl1,
                       ushort* __restrict__ Bt1, ushort* __restrict__ Bt2,
                       int* __restrict__ bfill) {
    int o = blockIdx.x * blockDim.x + threadIdx.x;
    if (o < 512) bfill[o] = 0;
    if (o >= 32768) return;
    {   // Bt1: K=128, NCOLS=256: Bt[(k>>3)*256*8 + n*8 + (k&7)]
        int k0 = o & 7, n = (o >> 3) & 255, k8 = o >> 11;
        Bt1[o] = f2bf(W2[(size_t)(k8 * 8 + k0) * 256 + n]);
    }
    {   // Bt2: K=256, NCOLS=128, permuted within 32-k chunks
        int j = o & 7, n = (o >> 3) & 127, kc8 = o >> 10;   // kc8 = c*4+quad
        int c = kc8 >> 2, quad = kc8 & 3;
        int s = quad * 8 + j;
        int k = c * 32 + (s >> 1) + 16 * (s & 1);
        Bt2[o] = f2bf(Wl1[(size_t)k * 128 + n]);
    }
}

// Phase 1: stream edges once, partition into 391 dst-buckets.
// Per-wave LDS counters (4 copies) cut same-address atomic serialization.
__global__ __launch_bounds__(256) void k_part(const int* __restrict__ ei,
                                              const float* __restrict__ ew,
                                              int* __restrict__ bfill,
                                              uint2* __restrict__ stg,
                                              int E, int nbuck, int cap) {
    __shared__ int lcnt[4][512];
    __shared__ int lbase[4][512];
    int tid = threadIdx.x;
    int wvid = tid >> 6;
    for (int i = tid; i < nbuck; i += 256) {
        lcnt[0][i] = 0; lcnt[1][i] = 0; lcnt[2][i] = 0; lcnt[3][i] = 0;
    }
    __syncthreads();
    bool is64 = (ei[1] == 0) && (ei[3] == 0) && (ei[5] == 0) && (ei[7] == 0);
    int e0 = blockIdx.x * 2048;
    uint pack[8]; uint wb[8]; int bkt[8]; int rank[8];
    for (int u = 0; u < 8; u++) {
        int e = e0 + u * 256 + tid;
        bkt[u] = -1;
        if (e < E) {
            int s, d;
            if (is64) { s = ei[2 * e]; d = ei[2 * (E + e)]; }
            else      { s = ei[e];     d = ei[E + e]; }
            bkt[u] = d >> BSHIFT;
            pack[u] = ((uint)(d & (BNODES - 1)) << SRCBITS) | (uint)s;
            wb[u] = __float_as_uint(ew[e]);
            rank[u] = atomicAdd(&lcnt[wvid][bkt[u]], 1);
        }
    }
    __syncthreads();
    for (int i = tid; i < nbuck; i += 256) {
        int t0 = lcnt[0][i], t1 = lcnt[1][i], t2 = lcnt[2][i], t3 = lcnt[3][i];
        int tot = t0 + t1 + t2 + t3;
        int base = tot ? atomicAdd(&bfill[i], tot) : 0;
        lbase[0][i] = base;
        lbase[1][i] = base + t0;
        lbase[2][i] = base + t0 + t1;
        lbase[3][i] = base + t0 + t1 + t2;
    }
    __syncthreads();
    for (int u = 0; u < 8; u++)
        if (bkt[u] >= 0)
            stg[(size_t)bkt[u] * cap + lbase[wvid][bkt[u]] + rank[u]] =
                make_uint2(pack[u], wb[u]);
}

// Phase 2: one 512-thread block per 256-node bucket. Inline cvbase reduction
// (masked block-reduce over bfill) -> LDS count -> scan -> ranked scatter into
// the bucket's private ~32KB cv window. Fused: rowptr emission + deg/dis/p.
__global__ __launch_bounds__(512) void k_fine(const uint2* __restrict__ stg,
                                              const int* __restrict__ bfill,
                                              const float* __restrict__ x,
                                              float* __restrict__ dis,
                                              float* __restrict__ p,
                                              int* __restrict__ rowptr,
                                              int2* __restrict__ cv,
                                              int cap, int N, int E, int nbuck) {
    __shared__ int cnt_l[BNODES];
    __shared__ int base_l[BNODES];
    __shared__ float degf[BNODES];
    __shared__ int wsum[8];
    int b = blockIdx.x, tid = threadIdx.x;
    int lane = tid & 63, wvid = tid >> 6;
    // cvbase[b] = sum_{i<b} bfill[i] via masked block reduction
    int a = (tid < b && tid < nbuck) ? bfill[tid] : 0;   // nbuck <= 512
    for (int off = 32; off > 0; off >>= 1) a += __shfl_xor(a, off);
    if (lane == 0) wsum[wvid] = a;
    __syncthreads();
    int cb = wsum[0] + wsum[1] + wsum[2] + wsum[3] +
             wsum[4] + wsum[5] + wsum[6] + wsum[7];
    int n = bfill[b];
    if (b == nbuck - 1 && tid == 0) rowptr[N] = E;
    const uint2* s = stg + (size_t)b * cap;
    if (tid < BNODES) { cnt_l[tid] = 0; degf[tid] = 1.0f; }
    __syncthreads();
    for (int i = tid; i < n; i += 512)
        atomicAdd(&cnt_l[s[i].x >> SRCBITS], 1);
    __syncthreads();
    int c = 0;
    if (tid < BNODES) { c = cnt_l[tid]; cnt_l[tid] = 0; }  // reuse as fill ctr
    int v = c;
    for (int off = 1; off < 64; off <<= 1) {
        int u = __shfl_up(v, off);
        if (lane >= off) v += u;
    }
    if (wvid < 4 && lane == 63) wsum[wvid] = v;
    __syncthreads();
    if (tid < BNODES) {
        int wpre = 0;
        for (int k = 0; k < wvid; k++) wpre += wsum[k];
        base_l[tid] = v + wpre - c;
    }
    __syncthreads();
    for (int i = tid; i < n; i += 512) {
        uint2 r = s[i];
        int dl = r.x >> SRCBITS;
        int src = (int)(r.x & ((1u << SRCBITS) - 1));
        int pos = cb + base_l[dl] + atomicAdd(&cnt_l[dl], 1);
        cv[pos] = make_int2(src, (int)r.y);
        atomicAdd(&degf[dl], __uint_as_float(r.y));
    }
    __syncthreads();
    int gid = (b << BSHIFT) + tid;
    if (tid < BNODES && gid < N) {
        rowptr[gid] = cb + base_l[tid];
        float r = rsqrtf(degf[tid]);
        dis[gid] = r;
        p[gid] = r * x[gid];
    }
}

// Quarter-wave per node: q = sum(val*p[col]); t = dis*(q+p); tp = (t, dis).
__global__ __launch_bounds__(256) void k_q(const int* __restrict__ rowptr,
                                           const int2* __restrict__ cv,
                                           const float* __restrict__ dis,
                                           const float* __restrict__ p,
                                           float2* __restrict__ tp, int N) {
    int gid = blockIdx.x * blockDim.x + threadIdx.x;
    int wid = gid >> 4;
    int sl = threadIdx.x & 15;
    if (wid >= N) return;
    int beg = rowptr[wid], end = rowptr[wid + 1];
    float s = 0.0f;
    for (int i = beg + sl; i < end; i += 16) {
        int2 pr = cv[i];
        s += __int_as_float(pr.y) * p[pr.x];
    }
    s += __shfl_xor(s, 1);
    s += __shfl_xor(s, 2);
    s += __shfl_xor(s, 4);
    s += __shfl_xor(s, 8);
    if (sl == 0) {
        float r = dis[wid];
        tp[wid] = make_float2(r * (s + p[wid]), r);
    }
}

// Wave per node, rank-1 reconstruction on PACKED fp32 (v_pk_fma/v_pk_max):
// per edge: 1 pk_fma (t*W1+b1) + 1 pk_max + 1 pk_fma (accumulate) = 3 inst.
// Per 64-edge batch: stage (wd,t) to wave-private LDS, broadcast-read via
// ds_read_b128 (2 edges/iter, 2x unrolled). Padding slots (0,0) add 0.
__global__ __launch_bounds__(256) void k_agg(const int* __restrict__ rowptr,
                                             const int2* __restrict__ cv,
                                             const float2* __restrict__ tp,
                                             const float* __restrict__ W1,
                                             const float* __restrict__ b1,
                                             uint* __restrict__ z, int N) {
    __shared__ float4 eb[4][32];       // 2 KB: per-wave (wd,t) x64 edge slots
    int tid = threadIdx.x;
    int wvid = tid >> 6, lane = tid & 63;
    int wid = (blockIdx.x * blockDim.x + tid) >> 6;
    if (wid >= N) return;
    f32x2 w1 = *(const f32x2*)(W1 + lane * 2);
    f32x2 bb = *(const f32x2*)(b1 + lane * 2);
    int beg = rowptr[wid], end = rowptr[wid + 1];
    f32x2 acc0 = {0.f, 0.f}, acc1 = {0.f, 0.f};
    for (int base = beg; base < end; base += 64) {
        int eidx = base + lane;
        float wd = 0.0f, tt = 0.0f;
        if (eidx < end) {
            int2 pr = cv[eidx];
            float2 tps = tp[pr.x];     // 8B gather, L2-resident (800 KB array)
            wd = __int_as_float(pr.y) * tps.y;   // w_e * dis_src
            tt = tps.x;                          // t_src
        }
        ((float2*)&eb[wvid][0])[lane] = make_float2(wd, tt);
        int m = min(64, end - base);
        const float4* ebp = &eb[wvid][0];
        int halves = (m + 1) >> 1;
        int u = 0;
        for (; u + 2 <= halves; u += 2) {
            float4 e2 = ebp[u];
            float4 e3 = ebp[u + 1];
            acc0 = pk_fma((f32x2){e2.x, e2.x},
                          pk_relu(pk_fma((f32x2){e2.y, e2.y}, w1, bb)), acc0);
            acc1 = pk_fma((f32x2){e2.z, e2.z},
                          pk_relu(pk_fma((f32x2){e2.w, e2.w}, w1, bb)), acc1);
            acc0 = pk_fma((f32x2){e3.x, e3.x},
                          pk_relu(pk_fma((f32x2){e3.y, e3.y}, w1, bb)), acc0);
            acc1 = pk_fma((f32x2){e3.z, e3.z},
                          pk_relu(pk_fma((f32x2){e3.w, e3.w}, w1, bb)), acc1);
        }
        if (u < halves) {
            float4 e2 = ebp[u];
            acc0 = pk_fma((f32x2){e2.x, e2.x},
                          pk_relu(pk_fma((f32x2){e2.y, e2.y}, w1, bb)), acc0);
            acc1 = pk_fma((f32x2){e2.z, e2.z},
                          pk_relu(pk_fma((f32x2){e2.w, e2.w}, w1, bb)), acc1);
        }
    }
    f32x2 acc = acc0 + acc1;
    float2 tpd = tp[wid];
    float rd = tpd.y;
    f32x2 self = pk_relu(pk_fma((f32x2){tpd.x, tpd.x}, w1, bb));
    f32x2 o = (acc + (f32x2){rd, rd} * self) * (f32x2){rd, rd};
    z[(size_t)wid * 64 + lane] = packbf(o.x, o.y);
}

// Fused MLP: out[i] = relu(relu(z[i]@W2+b2)@Wl1+bl1) . wl2 + bl2.
// 4 independent waves/block, 32 rows each; B-frags direct from global (L1-hot).
// C->A staging packs the lane's two h2 cols into one uint -> ds_write_b32;
// the induced k-permutation is baked into Bt2 (k_init).
__global__ __launch_bounds__(256) void k_mlp(const ushort* __restrict__ A,    // z bf16 [N][128]
                                             const ushort* __restrict__ Bt1,  // [16][256][8]
                                             const ushort* __restrict__ Bt2,  // [32][128][8] (k-permuted)
                                             const float* __restrict__ b2,
                                             const float* __restrict__ bl1,
                                             const float* __restrict__ wl2,
                                             const float* __restrict__ bl2,
                                             float* __restrict__ out, int M) {
    __shared__ ushort st[4][32][40];   // per-wave C->A staging; 80B row stride
    int tid = threadIdx.x;
    int wv = tid >> 6, lane = tid & 63;
    int l15 = lane & 15, quad = lane >> 4;
    int row0 = blockIdx.x * 128 + wv * 32;
    int r0 = row0 + l15;      r0 = r0 < M ? r0 : M - 1;   // clamp; stores guarded
    int r1 = row0 + 16 + l15; r1 = r1 < M ? r1 : M - 1;

    bf8_t a1[2][4];                       // all A1 frags resident (32 VGPR)
    for (int kc = 0; kc < 4; kc++) {
        a1[0][kc] = *(const bf8_t*)(A + (size_t)r0 * 128 + kc * 32 + quad * 8);
        a1[1][kc] = *(const bf8_t*)(A + (size_t)r1 * 128 + kc * 32 + quad * 8);
    }
    f32x4 acc2[2][8];
    for (int i = 0; i < 2; i++)
        for (int j = 0; j < 8; j++) acc2[i][j] = (f32x4){0.f, 0.f, 0.f, 0.f};

    for (int c = 0; c < 8; c++) {         // 32-col chunk of h2 == 32-k of GEMM2
        f32x4 acc1[2][2];
        for (int i = 0; i < 2; i++)
            for (int j = 0; j < 2; j++) acc1[i][j] = (f32x4){0.f, 0.f, 0.f, 0.f};
        for (int kc = 0; kc < 4; kc++)
            for (int nt = 0; nt < 2; nt++) {
                bf8_t b = *(const bf8_t*)(Bt1 +
                    ((size_t)(kc * 4 + quad) * 256 + c * 32 + nt * 16 + l15) * 8);
                acc1[0][nt] = __builtin_amdgcn_mfma_f32_16x16x32_bf16(a1[0][kc], b, acc1[0][nt], 0, 0, 0);
                acc1[1][nt] = __builtin_amdgcn_mfma_f32_16x16x32_bf16(a1[1][kc], b, acc1[1][nt], 0, 0, 0);
            }
        float bb0 = b2[c * 32 + l15];
        float bb1 = b2[c * 32 + 16 + l15];
        for (int mt = 0; mt < 2; mt++)
            for (int rg = 0; rg < 4; rg++)
                *(uint*)&st[wv][mt * 16 + quad * 4 + rg][2 * l15] =
                    packbf(fmaxf(acc1[mt][0][rg] + bb0, 0.f),
                           fmaxf(acc1[mt][1][rg] + bb1, 0.f));
        bf8_t a2_0 = *(const bf8_t*)&st[wv][l15][quad * 8];
        bf8_t a2_1 = *(const bf8_t*)&st[wv][16 + l15][quad * 8];
        for (int nt2 = 0; nt2 < 8; nt2++) {
            bf8_t b = *(const bf8_t*)(Bt2 +
                ((size_t)(c * 4 + quad) * 128 + nt2 * 16 + l15) * 8);
            acc2[0][nt2] = __builtin_amdgcn_mfma_f32_16x16x32_bf16(a2_0, b, acc2[0][nt2], 0, 0, 0);
            acc2[1][nt2] = __builtin_amdgcn_mfma_f32_16x16x32_bf16(a2_1, b, acc2[1][nt2], 0, 0, 0);
        }
    }
    float rs[2][4] = {};
    for (int nt2 = 0; nt2 < 8; nt2++) {
        int col = nt2 * 16 + l15;
        float bb = bl1[col], ww = wl2[col];
        for (int mt = 0; mt < 2; mt++)
            for (int rg = 0; rg < 4; rg++)
                rs[mt][rg] += fmaxf(acc2[mt][nt2][rg] + bb, 0.f) * ww;
    }
    float base = bl2[0];
    for (int mt = 0; mt < 2; mt++)
        for (int rg = 0; rg < 4; rg++) {
            float s = rs[mt][rg];
            s += __shfl_xor(s, 1);
            s += __shfl_xor(s, 2);
            s += __shfl_xor(s, 4);
            s += __shfl_xor(s, 8);
            int row = row0 + mt * 16 + quad * 4 + rg;
            if (l15 == 0 && row < M) out[row] = s + base;
        }
}

extern "C" void kernel_launch(void* const* d_in, const int* in_sizes, int n_in,
                              void* d_out, int out_size, void* d_ws, size_t ws_size,
                              hipStream_t stream) {
    const float* x   = (const float*)d_in[0];
    const int*   ei  = (const int*)d_in[1];
    const float* ew  = (const float*)d_in[2];
    const float* W1  = (const float*)d_in[3];
    const float* b1  = (const float*)d_in[4];
    const float* W2  = (const float*)d_in[5];
    const float* b2  = (const float*)d_in[6];
    const float* Wl1 = (const float*)d_in[7];
    const float* bl1 = (const float*)d_in[8];
    const float* Wl2 = (const float*)d_in[9];
    const float* bl2 = (const float*)d_in[10];
    float* out = (float*)d_out;
    const int N = in_sizes[0];
    const int E = in_sizes[2];

    const int nbuck = (N + BNODES - 1) >> BSHIFT;             // 391
    const int cap = ((E / nbuck) * 5) / 4 + 1024;             // +~32 sigma slack

    char* w = (char*)d_ws;
    size_t off = 0;
    auto alloc = [&](size_t bytes) -> void* {
        void* p = w + off;
        off = align256(off + bytes);
        return p;
    };
    uint*   z      = (uint*)alloc((size_t)N * 64 * 4);      // bf16 [N][128]
    float2* tp     = (float2*)alloc((size_t)N * 8);         // (t, dis)
    float*  dis    = (float*)alloc((size_t)N * 4);
    float*  p_     = (float*)alloc((size_t)N * 4);
    int*    rowptr = (int*)alloc((size_t)(N + 1) * 4);
    int2*   cv     = (int2*)alloc((size_t)E * 8);
    uint2*  stg    = (uint2*)alloc((size_t)nbuck * cap * 8);
    int*    bfill  = (int*)alloc(512 * 4);
    ushort* Bt1    = (ushort*)alloc(32768 * 2);
    ushort* Bt2    = (ushort*)alloc(32768 * 2);

    k_init<<<128, 256, 0, stream>>>(W2, Wl1, Bt1, Bt2, bfill);
    k_part<<<(E + 2047) / 2048, 256, 0, stream>>>(ei, ew, bfill, stg, E, nbuck, cap);
    k_fine<<<nbuck, 512, 0, stream>>>(stg, bfill, x, dis, p_, rowptr, cv, cap, N, E, nbuck);
    k_q<<<(N * 16 + 255) / 256, 256, 0, stream>>>(rowptr, cv, dis, p_, tp, N);
    k_agg<<<(N + 3) / 4, 256, 0, stream>>>(rowptr, cv, tp, W1, b1, z, N);
    k_mlp<<<(N + 127) / 128, 256, 0, stream>>>((const ushort*)z, Bt1, Bt2,
                                               b2, bl1, Wl2, bl2, out, N);
}